// Round 2
// baseline (1693.279 us; speedup 1.0000x reference)
//
#include <hip/hip_runtime.h>
#include <stdint.h>

#define S_  8
#define D_  2048
#define B_  2
#define N_  1024
#define SD_ 16384
#define JP_ 11    // 11 pairs of bf16 weight columns (22 columns)

__device__ __forceinline__ unsigned pack_bf16_rne(float a, float b) {
    unsigned ua = __float_as_uint(a);
    unsigned ub = __float_as_uint(b);
    ua += 0x7FFFu + ((ua >> 16) & 1u);   // round-to-nearest-even
    ub += 0x7FFFu + ((ub >> 16) & 1u);
    return (ua >> 16) | (ub & 0xFFFF0000u);
}

// ---------------------------------------------------------------------------
// prep: Wp[(s*11+jp)*2048 + d] = bf16pair( (gamma+1)*w[2jp], (gamma+1)*w[2jp+1] )
// One thread per packed OUTPUT element (180224 threads) so stores are perfectly
// coalesced and latency is hidden by thread count.
// jp 0..6  -> W_alpha cols 2jp, 2jp+1   (14 cols)
// jp 7..10 -> W_beta  cols 2(jp-7), 2(jp-7)+1  (8 cols)
// ---------------------------------------------------------------------------
extern "C" __global__ void krom_prep(const float* __restrict__ gamma,
                                     const float* __restrict__ Wa,
                                     const float* __restrict__ Wb,
                                     unsigned* __restrict__ Wp)
{
    const int u = blockIdx.x * 256 + threadIdx.x;   // = (s*11+jp)*2048 + d
    if (u >= JP_ * SD_) return;
    const int sj = u >> 11;          // s*11 + jp
    const int d  = u & 2047;
    const int s  = sj / JP_;
    const int jp = sj - s * JP_;
    const int i  = (s << 11) + d;    // row into (SD_) weight matrices
    const float g = gamma[i] + 1.0f;
    float w0, w1;
    if (jp < 7) {
        w0 = Wa[i * 14 + 2 * jp];
        w1 = Wa[i * 14 + 2 * jp + 1];
    } else {
        const int j = jp - 7;
        w0 = Wb[i * 8 + 2 * j];
        w1 = Wb[i * 8 + 2 * j + 1];
    }
    Wp[u] = pack_bf16_rne(g * w0, g * w1);
}

// ---------------------------------------------------------------------------
// Phase 1: matvec + ssq + epilogue -> M[s][t] per (b,n).  256 thr, 2 n/block.
// Each thread owns 8 d-values; r is loaded per-s and DISCARDED (no retention
// ballast) so VGPR stays under 128 -> 4 blocks/CU; entire 1024-block grid
// resident at once.
// ---------------------------------------------------------------------------
extern "C" __global__ void __launch_bounds__(256, 4)
krom_matvec(const float* __restrict__ res,
            const unsigned* __restrict__ Wp,
            const float* __restrict__ sa,     // static_alpha[14]
            const float* __restrict__ pre_s,  // pre_branch_scale[1]
            const float* __restrict__ res_s,  // residual_scale[1]
            const float* __restrict__ sb,     // static_beta[8]
            const float* __restrict__ hps,    // h_post_scale[1]
            float* __restrict__ Mbuf)         // [2048][64]
{
    const int tid = threadIdx.x;
    const int blk = blockIdx.x;           // 0..1023
    const int b   = blk >> 9;             // 512 n-pairs per b
    const int n0  = (blk & 511) * 2;
    const int d0  = tid * 8;              // 8 d-values per thread

    // acc[n][0..21] = matvec partials, acc[n][22] = ssq
    float acc[2][23];
#pragma unroll
    for (int n = 0; n < 2; ++n)
#pragma unroll
        for (int j = 0; j < 23; ++j) acc[n][j] = 0.0f;

#pragma unroll
    for (int s = 0; s < S_; ++s) {
        const float* pr = res + (((size_t)(b * S_ + s) * N_ + n0) * D_ + d0);
        const float4 a0 = *reinterpret_cast<const float4*>(pr);
        const float4 a1 = *reinterpret_cast<const float4*>(pr + 4);
        const float4 b0 = *reinterpret_cast<const float4*>(pr + D_);
        const float4 b1 = *reinterpret_cast<const float4*>(pr + D_ + 4);
        const float ra[8] = {a0.x, a0.y, a0.z, a0.w, a1.x, a1.y, a1.z, a1.w};
        const float rb[8] = {b0.x, b0.y, b0.z, b0.w, b1.x, b1.y, b1.z, b1.w};
#pragma unroll
        for (int k = 0; k < 8; ++k) {
            acc[0][22] = fmaf(ra[k], ra[k], acc[0][22]);
            acc[1][22] = fmaf(rb[k], rb[k], acc[1][22]);
        }
        const unsigned* pw = Wp + ((s * JP_) << 11) + d0;
#pragma unroll
        for (int jp = 0; jp < JP_; ++jp) {
            const uint4 u0 = *reinterpret_cast<const uint4*>(pw + (jp << 11));
            const uint4 u1 = *reinterpret_cast<const uint4*>(pw + (jp << 11) + 4);
            const unsigned uu[8] = {u0.x, u0.y, u0.z, u0.w, u1.x, u1.y, u1.z, u1.w};
#pragma unroll
            for (int k = 0; k < 8; ++k) {
                const float w0 = __uint_as_float(uu[k] << 16);
                const float w1 = __uint_as_float(uu[k] & 0xFFFF0000u);
                acc[0][2 * jp]     = fmaf(ra[k], w0, acc[0][2 * jp]);
                acc[0][2 * jp + 1] = fmaf(ra[k], w1, acc[0][2 * jp + 1]);
                acc[1][2 * jp]     = fmaf(rb[k], w0, acc[1][2 * jp]);
                acc[1][2 * jp + 1] = fmaf(rb[k], w1, acc[1][2 * jp + 1]);
            }
        }
    }

    // ---- block-wide reduction of 46 partials (4 waves)
    __shared__ float red[4][2][23];
    __shared__ float fin[2][23];
    const int wave = tid >> 6, lane = tid & 63;
#pragma unroll
    for (int n = 0; n < 2; ++n)
#pragma unroll
        for (int j = 0; j < 23; ++j) {
            float v = acc[n][j];
#pragma unroll
            for (int m = 1; m < 64; m <<= 1) v += __shfl_xor(v, m, 64);
            if (lane == 0) red[wave][n][j] = v;
        }
    __syncthreads();
    if (tid < 46) {
        const int n = tid / 23, j = tid - n * 23;
        fin[n][j] = red[0][n][j] + red[1][n][j] + red[2][n][j] + red[3][n][j];
    }
    __syncthreads();

    // ---- tiny epilogue math (2 threads, one per n)
    __shared__ float wpre[2][S_], bet[2][S_], pk3[2][3];
    if (tid < 2) {
        const int n = tid;
        const float inv   = rsqrtf(fmaxf(fin[n][22], 1e-24f));
        const float scale = inv * 128.0f;    // sqrt(16384)
        float c[22];
#pragma unroll
        for (int j = 0; j < 22; ++j) c[j] = fin[n][j] * scale;
        const float ps = pre_s[0], rs = res_s[0], hs = hps[0];
        // w_pre = softmax(ps*c[0:8] + sa[0:8])
        float lg[8], mx = -1e30f;
#pragma unroll
        for (int s = 0; s < 8; ++s) { lg[s] = ps * c[s] + sa[s]; mx = fmaxf(mx, lg[s]); }
        float sum = 0.0f;
#pragma unroll
        for (int s = 0; s < 8; ++s) { lg[s] = expf(lg[s] - mx); sum += lg[s]; }
        const float rsum = 1.0f / sum;
#pragma unroll
        for (int s = 0; s < 8; ++s) wpre[n][s] = lg[s] * rsum;
        // p_k = sigmoid(cr0 - cr1)
#pragma unroll
        for (int k = 0; k < 3; ++k) {
            float a0 = rs * c[8 + 2 * k] + sa[8 + 2 * k];
            float a1 = rs * c[9 + 2 * k] + sa[9 + 2 * k];
            pk3[n][k] = 1.0f / (1.0f + expf(a1 - a0));
        }
        // beta_t = sigmoid(hs*c[14+t] + sb[t])
#pragma unroll
        for (int t = 0; t < 8; ++t)
            bet[n][t] = 1.0f / (1.0f + expf(-(hs * c[14 + t] + sb[t])));
    }
    __syncthreads();

    // ---- M[s][t] = hres[s][t] + beta[t]*w_pre[s] -> global Mbuf
    if (tid < 128) {
        const int n = tid >> 6, e = tid & 63, s = e >> 3, t = e & 7;
        float h = 1.0f;
#pragma unroll
        for (int k = 0; k < 3; ++k) {
            int sbit = (s >> (2 - k)) & 1, tbit = (t >> (2 - k)) & 1;
            float pk = pk3[n][k];
            h *= (sbit == tbit) ? pk : (1.0f - pk);
        }
        Mbuf[(size_t)(blk * 2 + n) * 64 + e] = h + bet[n][t] * wpre[n][s];
    }
}

// ---------------------------------------------------------------------------
// Phase 2: out[(b*8+t), n, d] = sum_s M[s][t] * r[b,s,n,d]
// Pure streaming: low VGPR, 256 B LDS -> full occupancy, near-HBM-ceiling.
// 4096 blocks: (n_glob 0..2047) x (d-half 0..1)
// ---------------------------------------------------------------------------
extern "C" __global__ void __launch_bounds__(256, 4)
krom_apply(const float* __restrict__ res,
           const float* __restrict__ Mbuf,
           float* __restrict__ out)
{
    const int tid  = threadIdx.x;
    const int blk  = blockIdx.x;          // 0..4095
    const int ng   = blk >> 1;            // global n index: b*1024 + nn
    const int half = blk & 1;
    const int b    = ng >> 10, nn = ng & 1023;
    const int d0   = (half << 10) + tid * 4;

    __shared__ float Ms[64];              // M[s][t]
    if (tid < 64) Ms[tid] = Mbuf[(size_t)ng * 64 + tid];
    __syncthreads();

    float4 rr[S_];
#pragma unroll
    for (int s = 0; s < S_; ++s)
        rr[s] = *reinterpret_cast<const float4*>(
            res + (((size_t)(b * S_ + s) * N_ + nn) * D_ + d0));

#pragma unroll
    for (int t = 0; t < S_; ++t) {
        float ox = 0.0f, oy = 0.0f, oz = 0.0f, ow = 0.0f;
#pragma unroll
        for (int s = 0; s < S_; ++s) {
            const float m = Ms[s * 8 + t];
            ox = fmaf(m, rr[s].x, ox);
            oy = fmaf(m, rr[s].y, oy);
            oz = fmaf(m, rr[s].z, oz);
            ow = fmaf(m, rr[s].w, ow);
        }
        *reinterpret_cast<float4*>(
            out + (((size_t)(b * S_ + t) * N_ + nn) * D_ + d0)) =
            make_float4(ox, oy, oz, ow);
    }
}

extern "C" void kernel_launch(void* const* d_in, const int* in_sizes, int n_in,
                              void* d_out, int out_size, void* d_ws, size_t ws_size,
                              hipStream_t stream)
{
    (void)in_sizes; (void)n_in; (void)out_size; (void)ws_size;
    // input order per setup_inputs(): residuals, gamma, static_alpha, W_alpha,
    // pre_branch_scale, residual_scale, static_beta, W_beta, h_post_scale
    const float* residuals = (const float*)d_in[0];
    const float* gamma     = (const float*)d_in[1];
    const float* sa        = (const float*)d_in[2];
    const float* Wa        = (const float*)d_in[3];
    const float* pre_s     = (const float*)d_in[4];
    const float* res_s     = (const float*)d_in[5];
    const float* sb        = (const float*)d_in[6];
    const float* Wb        = (const float*)d_in[7];
    const float* hps       = (const float*)d_in[8];

    // workspace layout: Wp [0, 720896) ; Mbuf [720896, 1245184).  Total 1.19 MB.
    unsigned* Wp   = (unsigned*)d_ws;
    float*    Mbuf = (float*)((char*)d_ws + 720896);

    hipLaunchKernelGGL(krom_prep, dim3((JP_ * SD_ + 255) / 256), dim3(256), 0, stream,
                       gamma, Wa, Wb, Wp);
    hipLaunchKernelGGL(krom_matvec, dim3(B_ * N_ / 2), dim3(256), 0, stream,
                       residuals, Wp, sa, pre_s, res_s, sb, hps, Mbuf);
    hipLaunchKernelGGL(krom_apply, dim3(B_ * N_ * 2), dim3(256), 0, stream,
                       residuals, Mbuf, (float*)d_out);
}

// Round 3
// 328.702 us; speedup vs baseline: 5.1514x; 5.1514x over previous
//
#include <hip/hip_runtime.h>
#include <stdint.h>

#define S_  8
#define D_  2048
#define B_  2
#define N_  1024
#define SD_ 16384
#define JP_ 11    // 11 pairs of bf16 weight columns (22 columns)

__device__ __forceinline__ unsigned pack_bf16_rne(float a, float b) {
    unsigned ua = __float_as_uint(a);
    unsigned ub = __float_as_uint(b);
    ua += 0x7FFFu + ((ua >> 16) & 1u);   // round-to-nearest-even
    ub += 0x7FFFu + ((ub >> 16) & 1u);
    return (ua >> 16) | (ub & 0xFFFF0000u);
}

// ---------------------------------------------------------------------------
// prep: Wp[(s*11+jp)*2048 + d] = bf16pair( (gamma+1)*w[2jp], (gamma+1)*w[2jp+1] )
// One thread per packed OUTPUT element; coalesced stores.
// jp 0..6  -> W_alpha cols 2jp, 2jp+1   (14 cols)
// jp 7..10 -> W_beta  cols 2(jp-7), 2(jp-7)+1  (8 cols)
// ---------------------------------------------------------------------------
extern "C" __global__ void krom_prep(const float* __restrict__ gamma,
                                     const float* __restrict__ Wa,
                                     const float* __restrict__ Wb,
                                     unsigned* __restrict__ Wp)
{
    const int u = blockIdx.x * 256 + threadIdx.x;   // = (s*11+jp)*2048 + d
    if (u >= JP_ * SD_) return;
    const int sj = u >> 11;          // s*11 + jp
    const int d  = u & 2047;
    const int s  = sj / JP_;
    const int jp = sj - s * JP_;
    const int i  = (s << 11) + d;    // row into (SD_) weight matrices
    const float g = gamma[i] + 1.0f;
    float w0, w1;
    if (jp < 7) {
        w0 = Wa[i * 14 + 2 * jp];
        w1 = Wa[i * 14 + 2 * jp + 1];
    } else {
        const int j = jp - 7;
        w0 = Wb[i * 8 + 2 * j];
        w1 = Wb[i * 8 + 2 * j + 1];
    }
    Wp[u] = pack_bf16_rne(g * w0, g * w1);
}

// ---------------------------------------------------------------------------
// Phase 1: matvec + ssq + epilogue -> M[s][t] per (b,n).
// ONE n per block, 512 threads, 4 d/thread.  Per-thread state is only
// acc[23] + one float4 -> ~60 VGPR, no spill (round-2 spilled 2.2 GB of
// scratch with 46 accs).  acc indices depend only on fully-unrolled jp/k,
// never on the (possibly rolled) s loop -> cannot be runtime-indexed.
// ---------------------------------------------------------------------------
extern "C" __global__ void __launch_bounds__(512, 2)
krom_matvec(const float* __restrict__ res,
            const unsigned* __restrict__ Wp,
            const float* __restrict__ sa,     // static_alpha[14]
            const float* __restrict__ pre_s,  // pre_branch_scale[1]
            const float* __restrict__ res_s,  // residual_scale[1]
            const float* __restrict__ sb,     // static_beta[8]
            const float* __restrict__ hps,    // h_post_scale[1]
            float* __restrict__ Mbuf)         // [2048][64]
{
    const int tid = threadIdx.x;
    const int blk = blockIdx.x;           // 0..2047 = b*1024 + n
    const int b   = blk >> 10;
    const int n   = blk & 1023;
    const int d0  = tid * 4;              // 4 d-values per thread

    // acc[0..21] = matvec partials, acc[22] = ssq
    float acc[23];
#pragma unroll
    for (int j = 0; j < 23; ++j) acc[j] = 0.0f;

    for (int s = 0; s < S_; ++s) {
        const float4 v = *reinterpret_cast<const float4*>(
            res + (((size_t)(b * S_ + s) * N_ + n) * D_ + d0));
        const float ra[4] = {v.x, v.y, v.z, v.w};
#pragma unroll
        for (int k = 0; k < 4; ++k)
            acc[22] = fmaf(ra[k], ra[k], acc[22]);
        const unsigned* pw = Wp + ((s * JP_) << 11) + d0;
#pragma unroll
        for (int jp = 0; jp < JP_; ++jp) {
            const uint4 u = *reinterpret_cast<const uint4*>(pw + (jp << 11));
            const unsigned uu[4] = {u.x, u.y, u.z, u.w};
#pragma unroll
            for (int k = 0; k < 4; ++k) {
                const float w0 = __uint_as_float(uu[k] << 16);
                const float w1 = __uint_as_float(uu[k] & 0xFFFF0000u);
                acc[2 * jp]     = fmaf(ra[k], w0, acc[2 * jp]);
                acc[2 * jp + 1] = fmaf(ra[k], w1, acc[2 * jp + 1]);
            }
        }
    }

    // ---- block-wide reduction of 23 partials (8 waves)
    __shared__ float red[8][23];
    __shared__ float fin[23];
    const int wave = tid >> 6, lane = tid & 63;
#pragma unroll
    for (int j = 0; j < 23; ++j) {
        float v = acc[j];
#pragma unroll
        for (int m = 1; m < 64; m <<= 1) v += __shfl_xor(v, m, 64);
        if (lane == 0) red[wave][j] = v;
    }
    __syncthreads();
    if (tid < 23) {
        float v = 0.0f;
#pragma unroll
        for (int w = 0; w < 8; ++w) v += red[w][tid];
        fin[tid] = v;
    }
    __syncthreads();

    // ---- tiny epilogue math (1 thread)
    __shared__ float wpre[S_], bet[S_], pk3[3];
    if (tid == 0) {
        const float inv   = rsqrtf(fmaxf(fin[22], 1e-24f));
        const float scale = inv * 128.0f;    // sqrt(16384)
        float c[22];
#pragma unroll
        for (int j = 0; j < 22; ++j) c[j] = fin[j] * scale;
        const float ps = pre_s[0], rs = res_s[0], hs = hps[0];
        // w_pre = softmax(ps*c[0:8] + sa[0:8])
        float lg[8], mx = -1e30f;
#pragma unroll
        for (int s = 0; s < 8; ++s) { lg[s] = ps * c[s] + sa[s]; mx = fmaxf(mx, lg[s]); }
        float sum = 0.0f;
#pragma unroll
        for (int s = 0; s < 8; ++s) { lg[s] = expf(lg[s] - mx); sum += lg[s]; }
        const float rsum = 1.0f / sum;
#pragma unroll
        for (int s = 0; s < 8; ++s) wpre[s] = lg[s] * rsum;
        // p_k = sigmoid(cr0 - cr1)
#pragma unroll
        for (int k = 0; k < 3; ++k) {
            float a0 = rs * c[8 + 2 * k] + sa[8 + 2 * k];
            float a1 = rs * c[9 + 2 * k] + sa[9 + 2 * k];
            pk3[k] = 1.0f / (1.0f + expf(a1 - a0));
        }
        // beta_t = sigmoid(hs*c[14+t] + sb[t])
#pragma unroll
        for (int t = 0; t < 8; ++t)
            bet[t] = 1.0f / (1.0f + expf(-(hs * c[14 + t] + sb[t])));
    }
    __syncthreads();

    // ---- M[s][t] = hres[s][t] + beta[t]*w_pre[s] -> global Mbuf
    if (tid < 64) {
        const int s = tid >> 3, t = tid & 7;
        float h = 1.0f;
#pragma unroll
        for (int k = 0; k < 3; ++k) {
            int sbit = (s >> (2 - k)) & 1, tbit = (t >> (2 - k)) & 1;
            float pk = pk3[k];
            h *= (sbit == tbit) ? pk : (1.0f - pk);
        }
        Mbuf[(size_t)blk * 64 + tid] = h + bet[t] * wpre[s];
    }
}

// ---------------------------------------------------------------------------
// Phase 2: out[(b*8+t), n, d] = sum_s M[s][t] * r[b,s,n,d]
// Pure streaming: low VGPR, 256 B LDS -> full occupancy, near-HBM-ceiling.
// 4096 blocks: (n_glob 0..2047) x (d-half 0..1)
// ---------------------------------------------------------------------------
extern "C" __global__ void __launch_bounds__(256, 4)
krom_apply(const float* __restrict__ res,
           const float* __restrict__ Mbuf,
           float* __restrict__ out)
{
    const int tid  = threadIdx.x;
    const int blk  = blockIdx.x;          // 0..4095
    const int ng   = blk >> 1;            // global n index: b*1024 + nn
    const int half = blk & 1;
    const int b    = ng >> 10, nn = ng & 1023;
    const int d0   = (half << 10) + tid * 4;

    __shared__ float Ms[64];              // M[s][t]
    if (tid < 64) Ms[tid] = Mbuf[(size_t)ng * 64 + tid];
    __syncthreads();

    float4 rr[S_];
#pragma unroll
    for (int s = 0; s < S_; ++s)
        rr[s] = *reinterpret_cast<const float4*>(
            res + (((size_t)(b * S_ + s) * N_ + nn) * D_ + d0));

#pragma unroll
    for (int t = 0; t < S_; ++t) {
        float ox = 0.0f, oy = 0.0f, oz = 0.0f, ow = 0.0f;
#pragma unroll
        for (int s = 0; s < S_; ++s) {
            const float m = Ms[s * 8 + t];
            ox = fmaf(m, rr[s].x, ox);
            oy = fmaf(m, rr[s].y, oy);
            oz = fmaf(m, rr[s].z, oz);
            ow = fmaf(m, rr[s].w, ow);
        }
        *reinterpret_cast<float4*>(
            out + (((size_t)(b * S_ + t) * N_ + nn) * D_ + d0)) =
            make_float4(ox, oy, oz, ow);
    }
}

extern "C" void kernel_launch(void* const* d_in, const int* in_sizes, int n_in,
                              void* d_out, int out_size, void* d_ws, size_t ws_size,
                              hipStream_t stream)
{
    (void)in_sizes; (void)n_in; (void)out_size; (void)ws_size;
    // input order per setup_inputs(): residuals, gamma, static_alpha, W_alpha,
    // pre_branch_scale, residual_scale, static_beta, W_beta, h_post_scale
    const float* residuals = (const float*)d_in[0];
    const float* gamma     = (const float*)d_in[1];
    const float* sa        = (const float*)d_in[2];
    const float* Wa        = (const float*)d_in[3];
    const float* pre_s     = (const float*)d_in[4];
    const float* res_s     = (const float*)d_in[5];
    const float* sb        = (const float*)d_in[6];
    const float* Wb        = (const float*)d_in[7];
    const float* hps       = (const float*)d_in[8];

    // workspace layout: Wp [0, 720896) ; Mbuf [720896, 1245184).  Total 1.19 MB.
    unsigned* Wp   = (unsigned*)d_ws;
    float*    Mbuf = (float*)((char*)d_ws + 720896);

    hipLaunchKernelGGL(krom_prep, dim3((JP_ * SD_ + 255) / 256), dim3(256), 0, stream,
                       gamma, Wa, Wb, Wp);
    hipLaunchKernelGGL(krom_matvec, dim3(B_ * N_), dim3(512), 0, stream,
                       residuals, Wp, sa, pre_s, res_s, sb, hps, Mbuf);
    hipLaunchKernelGGL(krom_apply, dim3(B_ * N_ * 2), dim3(256), 0, stream,
                       residuals, Mbuf, (float*)d_out);
}

// Round 4
// 305.527 us; speedup vs baseline: 5.5422x; 1.0759x over previous
//
#include <hip/hip_runtime.h>
#include <stdint.h>

#define S_  8
#define D_  2048
#define B_  2
#define N_  1024
#define SD_ 16384
#define JP_ 11    // 11 pairs of bf16 weight columns (22 columns)

__device__ __forceinline__ unsigned pack_bf16_rne(float a, float b) {
    unsigned ua = __float_as_uint(a);
    unsigned ub = __float_as_uint(b);
    ua += 0x7FFFu + ((ua >> 16) & 1u);   // round-to-nearest-even
    ub += 0x7FFFu + ((ub >> 16) & 1u);
    return (ua >> 16) | (ub & 0xFFFF0000u);
}

// ---------------------------------------------------------------------------
// prep: Wp[(s*11+jp)*2048 + d] = bf16pair( (gamma+1)*w[2jp], (gamma+1)*w[2jp+1] )
// One thread per packed OUTPUT element; coalesced stores.
// jp 0..6  -> W_alpha cols 2jp, 2jp+1   (14 cols)
// jp 7..10 -> W_beta  cols 2(jp-7), 2(jp-7)+1  (8 cols)
// ---------------------------------------------------------------------------
extern "C" __global__ void krom_prep(const float* __restrict__ gamma,
                                     const float* __restrict__ Wa,
                                     const float* __restrict__ Wb,
                                     unsigned* __restrict__ Wp)
{
    const int u = blockIdx.x * 256 + threadIdx.x;   // = (s*11+jp)*2048 + d
    if (u >= JP_ * SD_) return;
    const int sj = u >> 11;          // s*11 + jp
    const int d  = u & 2047;
    const int s  = sj / JP_;
    const int jp = sj - s * JP_;
    const int i  = (s << 11) + d;    // row into (SD_) weight matrices
    const float g = gamma[i] + 1.0f;
    float w0, w1;
    if (jp < 7) {
        w0 = Wa[i * 14 + 2 * jp];
        w1 = Wa[i * 14 + 2 * jp + 1];
    } else {
        const int j = jp - 7;
        w0 = Wb[i * 8 + 2 * j];
        w1 = Wb[i * 8 + 2 * j + 1];
    }
    Wp[u] = pack_bf16_rne(g * w0, g * w1);
}

// ---------------------------------------------------------------------------
// Fused kernel: matvec + epilogue + apply for TWO n per block.
// 512 threads, 4 d/thread.  Phase 1: 46 accs/thread (proven non-spilling
// shape from round 0/3), each Wp uint4 feeds both n (halves L2 traffic).
// Phase 2: M[s][t] in LDS; re-read r (L2-hot, the block just touched it)
// and write out directly -> no second 134 MB HBM sweep, no Mbuf, no 3rd
// kernel launch.
// ---------------------------------------------------------------------------
extern "C" __global__ void __launch_bounds__(512, 2)
krom_fused(const float* __restrict__ res,
           const unsigned* __restrict__ Wp,
           const float* __restrict__ sa,     // static_alpha[14]
           const float* __restrict__ pre_s,  // pre_branch_scale[1]
           const float* __restrict__ res_s,  // residual_scale[1]
           const float* __restrict__ sb,     // static_beta[8]
           const float* __restrict__ hps,    // h_post_scale[1]
           float* __restrict__ out)
{
    const int tid = threadIdx.x;
    const int blk = blockIdx.x;           // 0..1023 = b*512 + pair
    const int b   = blk >> 9;
    const int n0  = (blk & 511) * 2;
    const int d0  = tid * 4;              // 4 d-values per thread

    // ---- phase 1: matvec + ssq ------------------------------------------
    // acc*[0..21] = matvec partials, acc*[22] = ssq
    float acc0[23], acc1[23];
#pragma unroll
    for (int j = 0; j < 23; ++j) { acc0[j] = 0.0f; acc1[j] = 0.0f; }

    for (int s = 0; s < S_; ++s) {
        const float* pr = res + (((size_t)(b * S_ + s) * N_ + n0) * D_ + d0);
        const float4 va = *reinterpret_cast<const float4*>(pr);
        const float4 vb = *reinterpret_cast<const float4*>(pr + D_);
        const float ra[4] = {va.x, va.y, va.z, va.w};
        const float rb[4] = {vb.x, vb.y, vb.z, vb.w};
#pragma unroll
        for (int k = 0; k < 4; ++k) {
            acc0[22] = fmaf(ra[k], ra[k], acc0[22]);
            acc1[22] = fmaf(rb[k], rb[k], acc1[22]);
        }
        const unsigned* pw = Wp + ((s * JP_) << 11) + d0;
#pragma unroll
        for (int jp = 0; jp < JP_; ++jp) {
            const uint4 u = *reinterpret_cast<const uint4*>(pw + (jp << 11));
            const unsigned uu[4] = {u.x, u.y, u.z, u.w};
#pragma unroll
            for (int k = 0; k < 4; ++k) {
                const float w0 = __uint_as_float(uu[k] << 16);
                const float w1 = __uint_as_float(uu[k] & 0xFFFF0000u);
                acc0[2 * jp]     = fmaf(ra[k], w0, acc0[2 * jp]);
                acc0[2 * jp + 1] = fmaf(ra[k], w1, acc0[2 * jp + 1]);
                acc1[2 * jp]     = fmaf(rb[k], w0, acc1[2 * jp]);
                acc1[2 * jp + 1] = fmaf(rb[k], w1, acc1[2 * jp + 1]);
            }
        }
    }

    // ---- block-wide reduction of 2x23 partials (8 waves) ----------------
    __shared__ float red[8][2][23];
    __shared__ float fin[2][23];
    const int wave = tid >> 6, lane = tid & 63;
#pragma unroll
    for (int j = 0; j < 23; ++j) {
        float v0 = acc0[j], v1 = acc1[j];
#pragma unroll
        for (int m = 1; m < 64; m <<= 1) {
            v0 += __shfl_xor(v0, m, 64);
            v1 += __shfl_xor(v1, m, 64);
        }
        if (lane == 0) { red[wave][0][j] = v0; red[wave][1][j] = v1; }
    }
    __syncthreads();
    if (tid < 46) {
        const int n = tid / 23, j = tid - n * 23;
        float v = 0.0f;
#pragma unroll
        for (int w = 0; w < 8; ++w) v += red[w][n][j];
        fin[n][j] = v;
    }
    __syncthreads();

    // ---- tiny epilogue math (2 threads, one per n) ----------------------
    __shared__ float wpre[2][S_], bet[2][S_], pk3[2][3];
    if (tid < 2) {
        const int n = tid;
        const float inv   = rsqrtf(fmaxf(fin[n][22], 1e-24f));
        const float scale = inv * 128.0f;    // sqrt(16384)
        float c[22];
#pragma unroll
        for (int j = 0; j < 22; ++j) c[j] = fin[n][j] * scale;
        const float ps = pre_s[0], rs = res_s[0], hs = hps[0];
        // w_pre = softmax(ps*c[0:8] + sa[0:8])
        float lg[8], mx = -1e30f;
#pragma unroll
        for (int s = 0; s < 8; ++s) { lg[s] = ps * c[s] + sa[s]; mx = fmaxf(mx, lg[s]); }
        float sum = 0.0f;
#pragma unroll
        for (int s = 0; s < 8; ++s) { lg[s] = expf(lg[s] - mx); sum += lg[s]; }
        const float rsum = 1.0f / sum;
#pragma unroll
        for (int s = 0; s < 8; ++s) wpre[n][s] = lg[s] * rsum;
        // p_k = sigmoid(cr0 - cr1)
#pragma unroll
        for (int k = 0; k < 3; ++k) {
            float a0 = rs * c[8 + 2 * k] + sa[8 + 2 * k];
            float a1 = rs * c[9 + 2 * k] + sa[9 + 2 * k];
            pk3[n][k] = 1.0f / (1.0f + expf(a1 - a0));
        }
        // beta_t = sigmoid(hs*c[14+t] + sb[t])
#pragma unroll
        for (int t = 0; t < 8; ++t)
            bet[n][t] = 1.0f / (1.0f + expf(-(hs * c[14 + t] + sb[t])));
    }
    __syncthreads();

    // ---- M[s][t] = hres[s][t] + beta[t]*w_pre[s] -> LDS -----------------
    __shared__ float Ms[2][S_][S_];
    if (tid < 128) {
        const int n = tid >> 6, e = tid & 63, s = e >> 3, t = e & 7;
        float h = 1.0f;
#pragma unroll
        for (int k = 0; k < 3; ++k) {
            int sbit = (s >> (2 - k)) & 1, tbit = (t >> (2 - k)) & 1;
            float pk = pk3[n][k];
            h *= (sbit == tbit) ? pk : (1.0f - pk);
        }
        Ms[n][s][t] = h + bet[n][t] * wpre[n][s];
    }
    __syncthreads();

    // ---- phase 2: out[(b*8+t), n, d] = sum_s M[s][t] * r[s][d] ----------
    // r re-read is L2-hot (this block just streamed these exact lines).
#pragma unroll
    for (int n = 0; n < 2; ++n) {
        float o[8][4];
#pragma unroll
        for (int t = 0; t < 8; ++t)
#pragma unroll
            for (int k = 0; k < 4; ++k) o[t][k] = 0.0f;

        for (int s = 0; s < S_; ++s) {
            const float4 rv = *reinterpret_cast<const float4*>(
                res + (((size_t)(b * S_ + s) * N_ + (n0 + n)) * D_ + d0));
            const float4 m0 = *reinterpret_cast<const float4*>(&Ms[n][s][0]);
            const float4 m1 = *reinterpret_cast<const float4*>(&Ms[n][s][4]);
            o[0][0] = fmaf(m0.x, rv.x, o[0][0]); o[0][1] = fmaf(m0.x, rv.y, o[0][1]);
            o[0][2] = fmaf(m0.x, rv.z, o[0][2]); o[0][3] = fmaf(m0.x, rv.w, o[0][3]);
            o[1][0] = fmaf(m0.y, rv.x, o[1][0]); o[1][1] = fmaf(m0.y, rv.y, o[1][1]);
            o[1][2] = fmaf(m0.y, rv.z, o[1][2]); o[1][3] = fmaf(m0.y, rv.w, o[1][3]);
            o[2][0] = fmaf(m0.z, rv.x, o[2][0]); o[2][1] = fmaf(m0.z, rv.y, o[2][1]);
            o[2][2] = fmaf(m0.z, rv.z, o[2][2]); o[2][3] = fmaf(m0.z, rv.w, o[2][3]);
            o[3][0] = fmaf(m0.w, rv.x, o[3][0]); o[3][1] = fmaf(m0.w, rv.y, o[3][1]);
            o[3][2] = fmaf(m0.w, rv.z, o[3][2]); o[3][3] = fmaf(m0.w, rv.w, o[3][3]);
            o[4][0] = fmaf(m1.x, rv.x, o[4][0]); o[4][1] = fmaf(m1.x, rv.y, o[4][1]);
            o[4][2] = fmaf(m1.x, rv.z, o[4][2]); o[4][3] = fmaf(m1.x, rv.w, o[4][3]);
            o[5][0] = fmaf(m1.y, rv.x, o[5][0]); o[5][1] = fmaf(m1.y, rv.y, o[5][1]);
            o[5][2] = fmaf(m1.y, rv.z, o[5][2]); o[5][3] = fmaf(m1.y, rv.w, o[5][3]);
            o[6][0] = fmaf(m1.z, rv.x, o[6][0]); o[6][1] = fmaf(m1.z, rv.y, o[6][1]);
            o[6][2] = fmaf(m1.z, rv.z, o[6][2]); o[6][3] = fmaf(m1.z, rv.w, o[6][3]);
            o[7][0] = fmaf(m1.w, rv.x, o[7][0]); o[7][1] = fmaf(m1.w, rv.y, o[7][1]);
            o[7][2] = fmaf(m1.w, rv.z, o[7][2]); o[7][3] = fmaf(m1.w, rv.w, o[7][3]);
        }
#pragma unroll
        for (int t = 0; t < 8; ++t) {
            float* po = out + (((size_t)(b * S_ + t) * N_ + (n0 + n)) * D_ + d0);
            *reinterpret_cast<float4*>(po) = make_float4(o[t][0], o[t][1], o[t][2], o[t][3]);
        }
    }
}

extern "C" void kernel_launch(void* const* d_in, const int* in_sizes, int n_in,
                              void* d_out, int out_size, void* d_ws, size_t ws_size,
                              hipStream_t stream)
{
    (void)in_sizes; (void)n_in; (void)out_size; (void)ws_size;
    // input order per setup_inputs(): residuals, gamma, static_alpha, W_alpha,
    // pre_branch_scale, residual_scale, static_beta, W_beta, h_post_scale
    const float* residuals = (const float*)d_in[0];
    const float* gamma     = (const float*)d_in[1];
    const float* sa        = (const float*)d_in[2];
    const float* Wa        = (const float*)d_in[3];
    const float* pre_s     = (const float*)d_in[4];
    const float* res_s     = (const float*)d_in[5];
    const float* sb        = (const float*)d_in[6];
    const float* Wb        = (const float*)d_in[7];
    const float* hps       = (const float*)d_in[8];

    // workspace layout: Wp [0, 720896) only.
    unsigned* Wp = (unsigned*)d_ws;

    hipLaunchKernelGGL(krom_prep, dim3((JP_ * SD_ + 255) / 256), dim3(256), 0, stream,
                       gamma, Wa, Wb, Wp);
    hipLaunchKernelGGL(krom_fused, dim3(B_ * N_ / 2), dim3(512), 0, stream,
                       residuals, Wp, sa, pre_s, res_s, sb, hps, (float*)d_out);
}

// Round 6
// 304.422 us; speedup vs baseline: 5.5623x; 1.0036x over previous
//
#include <hip/hip_runtime.h>
#include <stdint.h>

#define S_  8
#define D_  2048
#define B_  2
#define N_  1024
#define SD_ 16384
#define JP_ 11    // 11 pairs of bf16 weight columns (22 columns)
#define NP_ 4     // n-values per block

typedef float f32x4 __attribute__((ext_vector_type(4)));   // native vec for nontemporal store

__device__ __forceinline__ unsigned pack_bf16_rne(float a, float b) {
    unsigned ua = __float_as_uint(a);
    unsigned ub = __float_as_uint(b);
    ua += 0x7FFFu + ((ua >> 16) & 1u);   // round-to-nearest-even
    ub += 0x7FFFu + ((ub >> 16) & 1u);
    return (ua >> 16) | (ub & 0xFFFF0000u);
}

// ---------------------------------------------------------------------------
// prep: Wp[(s*11+jp)*2048 + d] = bf16pair( (gamma+1)*w[2jp], (gamma+1)*w[2jp+1] )
// ---------------------------------------------------------------------------
extern "C" __global__ void krom_prep(const float* __restrict__ gamma,
                                     const float* __restrict__ Wa,
                                     const float* __restrict__ Wb,
                                     unsigned* __restrict__ Wp)
{
    const int u = blockIdx.x * 256 + threadIdx.x;   // = (s*11+jp)*2048 + d
    if (u >= JP_ * SD_) return;
    const int sj = u >> 11;          // s*11 + jp
    const int d  = u & 2047;
    const int s  = sj / JP_;
    const int jp = sj - s * JP_;
    const int i  = (s << 11) + d;    // row into (SD_) weight matrices
    const float g = gamma[i] + 1.0f;
    float w0, w1;
    if (jp < 7) {
        w0 = Wa[i * 14 + 2 * jp];
        w1 = Wa[i * 14 + 2 * jp + 1];
    } else {
        const int j = jp - 7;
        w0 = Wb[i * 8 + 2 * j];
        w1 = Wb[i * 8 + 2 * j + 1];
    }
    Wp[u] = pack_bf16_rne(g * w0, g * w1);
}

// ---------------------------------------------------------------------------
// Fused kernel: matvec + epilogue + apply for FOUR n per block.
// 512 threads, 4 d/thread.  Each Wp uint4 feeds 8 fmaf (2 cols x 4 n):
// Wp wave-op count + L2 traffic halve vs the 2-n version (136us, latency-
// bound, nothing saturated).  acc[4][23]=92 regs -> ~120 VGPR, 4 waves/SIMD,
// grid 512 blocks = 2 blocks/CU resident.
// All acc indices are compile-time (n, jp, k fully unrolled; s rolled).
// ---------------------------------------------------------------------------
extern "C" __global__ void __launch_bounds__(512, 2)
krom_fused(const float* __restrict__ res,
           const unsigned* __restrict__ Wp,
           const float* __restrict__ sa,     // static_alpha[14]
           const float* __restrict__ pre_s,  // pre_branch_scale[1]
           const float* __restrict__ res_s,  // residual_scale[1]
           const float* __restrict__ sb,     // static_beta[8]
           const float* __restrict__ hps,    // h_post_scale[1]
           float* __restrict__ out)
{
    const int tid = threadIdx.x;
    const int blk = blockIdx.x;           // 0..511 = b*256 + quad
    const int b   = blk >> 8;
    const int n0  = (blk & 255) * NP_;
    const int d0  = tid * 4;              // 4 d-values per thread

    // ---- phase 1: matvec + ssq ------------------------------------------
    // acc[n][0..21] = matvec partials, acc[n][22] = ssq
    float acc[NP_][23];
#pragma unroll
    for (int n = 0; n < NP_; ++n)
#pragma unroll
        for (int j = 0; j < 23; ++j) acc[n][j] = 0.0f;

    for (int s = 0; s < S_; ++s) {
        const float* pr = res + (((size_t)(b * S_ + s) * N_ + n0) * D_ + d0);
        float rr[NP_][4];
#pragma unroll
        for (int n = 0; n < NP_; ++n) {
            const float4 v = *reinterpret_cast<const float4*>(pr + (size_t)n * D_);
            rr[n][0] = v.x; rr[n][1] = v.y; rr[n][2] = v.z; rr[n][3] = v.w;
#pragma unroll
            for (int k = 0; k < 4; ++k)
                acc[n][22] = fmaf(rr[n][k], rr[n][k], acc[n][22]);
        }
        const unsigned* pw = Wp + ((s * JP_) << 11) + d0;
#pragma unroll
        for (int jp = 0; jp < JP_; ++jp) {
            const uint4 u = *reinterpret_cast<const uint4*>(pw + (jp << 11));
            const unsigned uu[4] = {u.x, u.y, u.z, u.w};
#pragma unroll
            for (int k = 0; k < 4; ++k) {
                const float w0 = __uint_as_float(uu[k] << 16);
                const float w1 = __uint_as_float(uu[k] & 0xFFFF0000u);
#pragma unroll
                for (int n = 0; n < NP_; ++n) {
                    acc[n][2 * jp]     = fmaf(rr[n][k], w0, acc[n][2 * jp]);
                    acc[n][2 * jp + 1] = fmaf(rr[n][k], w1, acc[n][2 * jp + 1]);
                }
            }
        }
    }

    // ---- block-wide reduction of 4x23 partials (8 waves) ----------------
    __shared__ float red[8][NP_][23];
    __shared__ float fin[NP_][23];
    const int wave = tid >> 6, lane = tid & 63;
#pragma unroll
    for (int n = 0; n < NP_; ++n)
#pragma unroll
        for (int j = 0; j < 23; ++j) {
            float v = acc[n][j];
#pragma unroll
            for (int m = 1; m < 64; m <<= 1) v += __shfl_xor(v, m, 64);
            if (lane == 0) red[wave][n][j] = v;
        }
    __syncthreads();
    if (tid < NP_ * 23) {
        const int n = tid / 23, j = tid - n * 23;
        float v = 0.0f;
#pragma unroll
        for (int w = 0; w < 8; ++w) v += red[w][n][j];
        fin[n][j] = v;
    }
    __syncthreads();

    // ---- tiny epilogue math (4 threads, one per n) ----------------------
    __shared__ float wpre[NP_][S_], bet[NP_][S_], pk3[NP_][3];
    if (tid < NP_) {
        const int n = tid;
        const float inv   = rsqrtf(fmaxf(fin[n][22], 1e-24f));
        const float scale = inv * 128.0f;    // sqrt(16384)
        float c[22];
#pragma unroll
        for (int j = 0; j < 22; ++j) c[j] = fin[n][j] * scale;
        const float ps = pre_s[0], rs = res_s[0], hs = hps[0];
        // w_pre = softmax(ps*c[0:8] + sa[0:8])
        float lg[8], mx = -1e30f;
#pragma unroll
        for (int s = 0; s < 8; ++s) { lg[s] = ps * c[s] + sa[s]; mx = fmaxf(mx, lg[s]); }
        float sum = 0.0f;
#pragma unroll
        for (int s = 0; s < 8; ++s) { lg[s] = expf(lg[s] - mx); sum += lg[s]; }
        const float rsum = 1.0f / sum;
#pragma unroll
        for (int s = 0; s < 8; ++s) wpre[n][s] = lg[s] * rsum;
        // p_k = sigmoid(cr0 - cr1)
#pragma unroll
        for (int k = 0; k < 3; ++k) {
            float a0 = rs * c[8 + 2 * k] + sa[8 + 2 * k];
            float a1 = rs * c[9 + 2 * k] + sa[9 + 2 * k];
            pk3[n][k] = 1.0f / (1.0f + expf(a1 - a0));
        }
        // beta_t = sigmoid(hs*c[14+t] + sb[t])
#pragma unroll
        for (int t = 0; t < 8; ++t)
            bet[n][t] = 1.0f / (1.0f + expf(-(hs * c[14 + t] + sb[t])));
    }
    __syncthreads();

    // ---- M[s][t] = hres[s][t] + beta[t]*w_pre[s] -> LDS -----------------
    __shared__ float Ms[NP_][S_][S_];
    if (tid < NP_ * 64) {
        const int n = tid >> 6, e = tid & 63, s = e >> 3, t = e & 7;
        float h = 1.0f;
#pragma unroll
        for (int k = 0; k < 3; ++k) {
            int sbit = (s >> (2 - k)) & 1, tbit = (t >> (2 - k)) & 1;
            float pk = pk3[n][k];
            h *= (sbit == tbit) ? pk : (1.0f - pk);
        }
        Ms[n][s][t] = h + bet[n][t] * wpre[n][s];
    }
    __syncthreads();

    // ---- phase 2: out[(b*8+t), n, d] = sum_s M[s][t] * r[s][d] ----------
    // r re-read is L2/L3-hot (this block just streamed these lines).
    // Output stores are nontemporal: don't evict L2-resident Wp with the
    // 134 MB streaming write.
#pragma unroll
    for (int n = 0; n < NP_; ++n) {
        float o[8][4];
#pragma unroll
        for (int t = 0; t < 8; ++t)
#pragma unroll
            for (int k = 0; k < 4; ++k) o[t][k] = 0.0f;

        for (int s = 0; s < S_; ++s) {
            const float4 rv = *reinterpret_cast<const float4*>(
                res + (((size_t)(b * S_ + s) * N_ + (n0 + n)) * D_ + d0));
            const float4 m0 = *reinterpret_cast<const float4*>(&Ms[n][s][0]);
            const float4 m1 = *reinterpret_cast<const float4*>(&Ms[n][s][4]);
            o[0][0] = fmaf(m0.x, rv.x, o[0][0]); o[0][1] = fmaf(m0.x, rv.y, o[0][1]);
            o[0][2] = fmaf(m0.x, rv.z, o[0][2]); o[0][3] = fmaf(m0.x, rv.w, o[0][3]);
            o[1][0] = fmaf(m0.y, rv.x, o[1][0]); o[1][1] = fmaf(m0.y, rv.y, o[1][1]);
            o[1][2] = fmaf(m0.y, rv.z, o[1][2]); o[1][3] = fmaf(m0.y, rv.w, o[1][3]);
            o[2][0] = fmaf(m0.z, rv.x, o[2][0]); o[2][1] = fmaf(m0.z, rv.y, o[2][1]);
            o[2][2] = fmaf(m0.z, rv.z, o[2][2]); o[2][3] = fmaf(m0.z, rv.w, o[2][3]);
            o[3][0] = fmaf(m0.w, rv.x, o[3][0]); o[3][1] = fmaf(m0.w, rv.y, o[3][1]);
            o[3][2] = fmaf(m0.w, rv.z, o[3][2]); o[3][3] = fmaf(m0.w, rv.w, o[3][3]);
            o[4][0] = fmaf(m1.x, rv.x, o[4][0]); o[4][1] = fmaf(m1.x, rv.y, o[4][1]);
            o[4][2] = fmaf(m1.x, rv.z, o[4][2]); o[4][3] = fmaf(m1.x, rv.w, o[4][3]);
            o[5][0] = fmaf(m1.y, rv.x, o[5][0]); o[5][1] = fmaf(m1.y, rv.y, o[5][1]);
            o[5][2] = fmaf(m1.y, rv.z, o[5][2]); o[5][3] = fmaf(m1.y, rv.w, o[5][3]);
            o[6][0] = fmaf(m1.z, rv.x, o[6][0]); o[6][1] = fmaf(m1.z, rv.y, o[6][1]);
            o[6][2] = fmaf(m1.z, rv.z, o[6][2]); o[6][3] = fmaf(m1.z, rv.w, o[6][3]);
            o[7][0] = fmaf(m1.w, rv.x, o[7][0]); o[7][1] = fmaf(m1.w, rv.y, o[7][1]);
            o[7][2] = fmaf(m1.w, rv.z, o[7][2]); o[7][3] = fmaf(m1.w, rv.w, o[7][3]);
        }
#pragma unroll
        for (int t = 0; t < 8; ++t) {
            float* po = out + (((size_t)(b * S_ + t) * N_ + (n0 + n)) * D_ + d0);
            f32x4 ov = {o[t][0], o[t][1], o[t][2], o[t][3]};
            __builtin_nontemporal_store(ov, reinterpret_cast<f32x4*>(po));
        }
    }
}

extern "C" void kernel_launch(void* const* d_in, const int* in_sizes, int n_in,
                              void* d_out, int out_size, void* d_ws, size_t ws_size,
                              hipStream_t stream)
{
    (void)in_sizes; (void)n_in; (void)out_size; (void)ws_size;
    // input order per setup_inputs(): residuals, gamma, static_alpha, W_alpha,
    // pre_branch_scale, residual_scale, static_beta, W_beta, h_post_scale
    const float* residuals = (const float*)d_in[0];
    const float* gamma     = (const float*)d_in[1];
    const float* sa        = (const float*)d_in[2];
    const float* Wa        = (const float*)d_in[3];
    const float* pre_s     = (const float*)d_in[4];
    const float* res_s     = (const float*)d_in[5];
    const float* sb        = (const float*)d_in[6];
    const float* Wb        = (const float*)d_in[7];
    const float* hps       = (const float*)d_in[8];

    // workspace layout: Wp [0, 720896) only.
    unsigned* Wp = (unsigned*)d_ws;

    hipLaunchKernelGGL(krom_prep, dim3((JP_ * SD_ + 255) / 256), dim3(256), 0, stream,
                       gamma, Wa, Wb, Wp);
    hipLaunchKernelGGL(krom_fused, dim3(B_ * N_ / NP_), dim3(512), 0, stream,
                       residuals, Wp, sa, pre_s, res_s, sb, hps, (float*)d_out);
}